// Round 2
// baseline (774.681 us; speedup 1.0000x reference)
//
#include <hip/hip_runtime.h>
#include <hip/hip_bf16.h>

// Problem constants: B=4, S=1024, D=1024, H=16, HD=64
constexpr int Bc = 4, Sc = 1024, Dc = 1024, Hc = 16, HDc = 64;
constexpr long BSD = (long)Bc * Sc * Dc;      // 4,194,304

typedef __attribute__((ext_vector_type(8))) short bf16x8;   // 8 bf16 = 4 VGPRs
typedef __attribute__((ext_vector_type(4))) float f32x4;

__device__ inline ushort f2bf(float f) {  // round-to-nearest-even
    union { float f; unsigned i; } v; v.f = f;
    unsigned lsb = (v.i >> 16) & 1;
    v.i += 0x7fffu + lsb;
    return (ushort)(v.i >> 16);
}

__device__ inline bf16x8 frag_bf16(const ushort* p) { return *(const bf16x8*)p; }
__device__ inline bf16x8 frag_f32(const float* p) {
    f32x4 x0 = *(const f32x4*)p;
    f32x4 x1 = *(const f32x4*)(p + 4);
    bf16x8 r;
    #pragma unroll
    for (int i = 0; i < 4; i++) { r[i] = (short)f2bf(x0[i]); r[i + 4] = (short)f2bf(x1[i]); }
    return r;
}

// ---------------------------------------------------------------------------
// fp32 -> bf16 elementwise convert (n must be a multiple of 8)
// ---------------------------------------------------------------------------
__global__ __launch_bounds__(256)
void cvt_f32_bf16(const float* __restrict__ src, ushort* __restrict__ dst, int n)
{
    const int i = (blockIdx.x * 256 + threadIdx.x) * 8;
    if (i >= n) return;
    f32x4 a = *(const f32x4*)(src + i);
    f32x4 b = *(const f32x4*)(src + i + 4);
    bf16x8 r;
    #pragma unroll
    for (int j = 0; j < 4; j++) { r[j] = (short)f2bf(a[j]); r[j + 4] = (short)f2bf(b[j]); }
    *(bf16x8*)(dst + i) = r;
}

// ---------------------------------------------------------------------------
// C[m,n] = sum_k A[m,k]*Bt[n,k] (+bias[n]).  A: bf16 or fp32 (AF32, converted
// inline); Bt: bf16; acc fp32; out bf16 or fp32 (OUTF32).
// Block = 256 threads (4 waves, 2x2), block tile 64x64, wave tile 32x32.
// MODE 0: C[z*sC + m*ldc + n]
// MODE 1: V-transpose store: Vt[b,h,d,s]      (z==0, bf16 out)
// MODE 2: ctx store: C[b*S*D + m*D + h*HD + n] with z = b*H + h
// ---------------------------------------------------------------------------
template<int MODE, bool AF32, bool OUTF32>
__global__ __launch_bounds__(256)
void gemm_bt(const void* __restrict__ Av, int lda, long sA,
             const ushort* __restrict__ Bt, int ldb, long sB,
             const float* __restrict__ bias,
             void* __restrict__ Cv, int ldc, long sC,
             int K)
{
    const int z = blockIdx.z;
    Bt += (long)z * sB;

    const int lane = threadIdx.x & 63;
    const int wave = threadIdx.x >> 6;
    const int wr = wave >> 1, wc = wave & 1;
    const int mbase = blockIdx.y * 64 + wr * 32;
    const int nbase = blockIdx.x * 64 + wc * 32;
    const int l15 = lane & 15, quad = lane >> 4;

    f32x4 acc00 = {}, acc01 = {}, acc10 = {}, acc11 = {};

    const ushort* Ab = (const ushort*)Av + (AF32 ? 0 : (long)z * sA);
    const float*  Af = (const float*)Av + (AF32 ? (long)z * sA : 0);

    const ushort* ab0 = Ab + (long)(mbase      + l15) * lda + quad * 8;
    const ushort* ab1 = Ab + (long)(mbase + 16 + l15) * lda + quad * 8;
    const float*  af0 = Af + (long)(mbase      + l15) * lda + quad * 8;
    const float*  af1 = Af + (long)(mbase + 16 + l15) * lda + quad * 8;
    const ushort* bb0 = Bt + (long)(nbase      + l15) * ldb + quad * 8;
    const ushort* bb1 = Bt + (long)(nbase + 16 + l15) * ldb + quad * 8;

    for (int k0 = 0; k0 < K; k0 += 32) {
        bf16x8 a0 = AF32 ? frag_f32(af0 + k0) : frag_bf16(ab0 + k0);
        bf16x8 a1 = AF32 ? frag_f32(af1 + k0) : frag_bf16(ab1 + k0);
        bf16x8 b0 = frag_bf16(bb0 + k0);
        bf16x8 b1 = frag_bf16(bb1 + k0);
        acc00 = __builtin_amdgcn_mfma_f32_16x16x32_bf16(a0, b0, acc00, 0, 0, 0);
        acc01 = __builtin_amdgcn_mfma_f32_16x16x32_bf16(a0, b1, acc01, 0, 0, 0);
        acc10 = __builtin_amdgcn_mfma_f32_16x16x32_bf16(a1, b0, acc10, 0, 0, 0);
        acc11 = __builtin_amdgcn_mfma_f32_16x16x32_bf16(a1, b1, acc11, 0, 0, 0);
    }

    // Epilogue. C/D layout: col = lane&15, row = quad*4 + reg.
    f32x4 accs[2][2] = { {acc00, acc01}, {acc10, acc11} };
    #pragma unroll
    for (int mt = 0; mt < 2; mt++) {
        #pragma unroll
        for (int nt = 0; nt < 2; nt++) {
            const int row0 = mbase + mt * 16 + quad * 4;
            const int col  = nbase + nt * 16 + l15;
            const float bv = bias ? bias[col] : 0.0f;
            #pragma unroll
            for (int i = 0; i < 4; i++) {
                const float vv = accs[mt][nt][i] + bv;
                const int r = row0 + i;
                if (MODE == 0) {
                    if (OUTF32) ((float*)Cv)[(long)z * sC + (long)r * ldc + col] = vv;
                    else        ((ushort*)Cv)[(long)z * sC + (long)r * ldc + col] = f2bf(vv);
                } else if (MODE == 1) {
                    // r = b*S + s ; col = h*HD + d  ->  Vt[((b*H+h)*HD + d)*S + s]
                    const int b = r >> 10, s = r & 1023;
                    const int h = col >> 6, d = col & 63;
                    ((ushort*)Cv)[(long)((b * Hc + h) * HDc + d) * Sc + s] = f2bf(vv);
                } else {
                    // z = b*H + h ; ctx[b, r, h*HD + col]  (fp32)
                    const int b = z >> 4, h = z & 15;
                    ((float*)Cv)[(long)b * Sc * Dc + (long)r * Dc + h * HDc + col] = vv;
                }
            }
        }
    }
}

// ---------------------------------------------------------------------------
// Fused scores + mask + softmax -> writes fp32 attn (the 2nd output).
// Grid: (S/16 q-blocks, B*H). Block 256 (4 waves). WG owns 16 q-rows, all 1024 k.
// ---------------------------------------------------------------------------
__global__ __launch_bounds__(256)
void attn_softmax(const ushort* __restrict__ Q, const ushort* __restrict__ Kp,
                  const int* __restrict__ mask, float* __restrict__ attn)
{
    __shared__ float sc[16][1024];   // 64 KB

    const int bh = blockIdx.y;
    const int b = bh >> 4, h = bh & 15;
    const int qbase = blockIdx.x * 16;
    const int lane = threadIdx.x & 63;
    const int wave = threadIdx.x >> 6;
    const int l15 = lane & 15, quad = lane >> 4;

    const ushort* Qh = Q  + (long)b * Sc * Dc + h * HDc;
    const ushort* Kh = Kp + (long)b * Sc * Dc + h * HDc;

    // A fragments for these 16 q-rows (K=HD=64 -> two k-steps), reused 16x.
    const ushort* qrow = Qh + (long)(qbase + l15) * Dc + quad * 8;
    const bf16x8 a0 = *(const bf16x8*)(qrow);
    const bf16x8 a1 = *(const bf16x8*)(qrow + 32);

    // Each wave computes 16 col-tiles (16 cols each) of the score strip.
    for (int t = 0; t < 16; t++) {
        const int ct = wave * 16 + t;
        const ushort* krow = Kh + (long)(ct * 16 + l15) * Dc + quad * 8;
        const bf16x8 b0 = *(const bf16x8*)(krow);
        const bf16x8 b1 = *(const bf16x8*)(krow + 32);
        f32x4 acc = {};
        acc = __builtin_amdgcn_mfma_f32_16x16x32_bf16(a0, b0, acc, 0, 0, 0);
        acc = __builtin_amdgcn_mfma_f32_16x16x32_bf16(a1, b1, acc, 0, 0, 0);
        const int col = ct * 16 + l15;
        #pragma unroll
        for (int i = 0; i < 4; i++) sc[quad * 4 + i][col] = acc[i];
    }
    __syncthreads();

    // Softmax: each wave handles 4 rows; 16 values per lane held in registers.
    for (int rr = 0; rr < 4; rr++) {
        const int r = wave * 4 + rr;
        float v[16];
        float mx = -3.0e38f;
        #pragma unroll
        for (int t = 0; t < 16; t++) {
            const int col = t * 64 + lane;
            float s = sc[r][col] * 0.125f;                 // 1/sqrt(64)
            if (mask[b * Sc + col] == 0) s = -1e10f;       // scale then mask (= ref)
            v[t] = s;
            mx = fmaxf(mx, s);
        }
        #pragma unroll
        for (int off = 32; off >= 1; off >>= 1) mx = fmaxf(mx, __shfl_xor(mx, off, 64));
        float sum = 0.0f;
        #pragma unroll
        for (int t = 0; t < 16; t++) { v[t] = __expf(v[t] - mx); sum += v[t]; }
        #pragma unroll
        for (int off = 32; off >= 1; off >>= 1) sum += __shfl_xor(sum, off, 64);
        const float inv = 1.0f / sum;
        float* arow = attn + ((long)bh * Sc + qbase + r) * Sc;
        #pragma unroll
        for (int t = 0; t < 16; t++) arow[t * 64 + lane] = v[t] * inv;
    }
}

// ---------------------------------------------------------------------------
extern "C" void kernel_launch(void* const* d_in, const int* in_sizes, int n_in,
                              void* d_out, int out_size, void* d_ws, size_t ws_size,
                              hipStream_t stream)
{
    const float* q    = (const float*)d_in[0];
    const float* k    = (const float*)d_in[1];
    const float* v    = (const float*)d_in[2];
    const int*   mask = (const int*)  d_in[3];
    const float* Wq   = (const float*)d_in[4];
    const float* bq   = (const float*)d_in[5];
    const float* Wk   = (const float*)d_in[6];
    const float* bk   = (const float*)d_in[7];
    const float* Wv   = (const float*)d_in[8];
    const float* bv   = (const float*)d_in[9];
    const float* Wo   = (const float*)d_in[10];
    const float* bo   = (const float*)d_in[11];

    // ws layout (ushort elems unless noted):
    ushort* ws  = (ushort*)d_ws;
    ushort* qb  = ws;                    // bf16 copies of q,k,v  (4M each)
    ushort* kb  = ws + BSD;
    ushort* vb  = ws + 2 * BSD;
    ushort* Wqb = ws + 3 * BSD;          // bf16 weights (1M each)
    ushort* Wkb = Wqb + Dc * Dc;
    ushort* Wvb = Wkb + Dc * Dc;
    ushort* Wob = Wvb + Dc * Dc;
    ushort* Qp  = ws + 4 * BSD;          // projected Q,K (bf16, 4M each)
    ushort* Kpp = Qp + BSD;
    ushort* Vt  = Kpp + BSD;             // Vt[b,h,d,s] bf16
    float*  Ctx = (float*)(Vt + BSD);    // ctx fp32 (4M floats, 16 MB)

    float* out  = (float*)d_out;         // output 0: (B,S,D) fp32
    float* attn = out + BSD;             // output 1: (B,H,S,S) fp32

    const dim3 blk(256);

    // fp32 -> bf16 converts
    cvt_f32_bf16<<<dim3(BSD / (256 * 8)), blk, 0, stream>>>(q, qb, (int)BSD);
    cvt_f32_bf16<<<dim3(BSD / (256 * 8)), blk, 0, stream>>>(k, kb, (int)BSD);
    cvt_f32_bf16<<<dim3(BSD / (256 * 8)), blk, 0, stream>>>(v, vb, (int)BSD);
    cvt_f32_bf16<<<dim3(Dc * Dc / (256 * 8)), blk, 0, stream>>>(Wq, Wqb, Dc * Dc);
    cvt_f32_bf16<<<dim3(Dc * Dc / (256 * 8)), blk, 0, stream>>>(Wk, Wkb, Dc * Dc);
    cvt_f32_bf16<<<dim3(Dc * Dc / (256 * 8)), blk, 0, stream>>>(Wv, Wvb, Dc * Dc);
    cvt_f32_bf16<<<dim3(Dc * Dc / (256 * 8)), blk, 0, stream>>>(Wo, Wob, Dc * Dc);

    // Projections: M=4096 (grid.y=64), N=1024 (grid.x=16), K=1024.
    gemm_bt<0, false, false><<<dim3(16, 64, 1), blk, 0, stream>>>(qb, Dc, 0, Wqb, Dc, 0, bq, Qp,  Dc, 0, Dc);
    gemm_bt<0, false, false><<<dim3(16, 64, 1), blk, 0, stream>>>(kb, Dc, 0, Wkb, Dc, 0, bk, Kpp, Dc, 0, Dc);
    gemm_bt<1, false, false><<<dim3(16, 64, 1), blk, 0, stream>>>(vb, Dc, 0, Wvb, Dc, 0, bv, Vt,  Dc, 0, Dc);

    // Scores + mask + softmax -> attn (fp32, into d_out).
    attn_softmax<<<dim3(Sc / 16, Bc * Hc, 1), blk, 0, stream>>>(Qp, Kpp, mask, attn);

    // ctx = attn @ V : batched over 64 (b,h); M=1024, N=64, K=1024. A is fp32.
    gemm_bt<2, true, true><<<dim3(1, 16, Bc * Hc), blk, 0, stream>>>(
        attn, Sc, (long)Sc * Sc, Vt, Sc, (long)HDc * Sc, nullptr, Ctx, 0, 0, Sc);

    // out = ctx @ Wo^T + bo -> d_out[0 : B*S*D]  (A fp32, out fp32).
    gemm_bt<0, true, true><<<dim3(16, 64, 1), blk, 0, stream>>>(Ctx, Dc, 0, Wob, Dc, 0, bo, out, Dc, 0, Dc);
}

// Round 3
// 611.116 us; speedup vs baseline: 1.2677x; 1.2677x over previous
//
#include <hip/hip_runtime.h>
#include <hip/hip_bf16.h>

// Problem constants: B=4, S=1024, D=1024, H=16, HD=64
constexpr int Bc = 4, Sc = 1024, Dc = 1024, Hc = 16, HDc = 64;
constexpr long BSD = (long)Bc * Sc * Dc;      // 4,194,304
constexpr long MM  = (long)Dc * Dc;           // 1,048,576

typedef __attribute__((ext_vector_type(8))) short bf16x8;   // 8 bf16 = 4 VGPRs
typedef __attribute__((ext_vector_type(4))) float f32x4;
typedef unsigned int u32;

__device__ inline ushort f2bf(float f) {  // round-to-nearest-even
    union { float f; unsigned i; } v; v.f = f;
    unsigned lsb = (v.i >> 16) & 1;
    v.i += 0x7fffu + lsb;
    return (ushort)(v.i >> 16);
}

__device__ inline bf16x8 frag_f32(const float* p) {
    f32x4 x0 = *(const f32x4*)p;
    f32x4 x1 = *(const f32x4*)(p + 4);
    bf16x8 r;
    #pragma unroll
    for (int i = 0; i < 4; i++) { r[i] = (short)f2bf(x0[i]); r[i + 4] = (short)f2bf(x1[i]); }
    return r;
}

// ---------------------------------------------------------------------------
// One-launch fp32 -> bf16 convert of q,k,v,Wq,Wk,Wv,Wo into ws.
// grid.y = tensor id (0..6); grid.x covers the largest tensor.
// ---------------------------------------------------------------------------
__global__ __launch_bounds__(256)
void cvt_all(const float* __restrict__ q, const float* __restrict__ k,
             const float* __restrict__ v, const float* __restrict__ Wq,
             const float* __restrict__ Wk, const float* __restrict__ Wv,
             const float* __restrict__ Wo, ushort* __restrict__ dst)
{
    const int t = blockIdx.y;
    const long n = (t < 3) ? BSD : MM;
    const long i = ((long)blockIdx.x * 256 + threadIdx.x) * 8;
    if (i >= n) return;
    const float* src; long off;
    switch (t) {
        case 0: src = q;  off = 0;            break;
        case 1: src = k;  off = BSD;          break;
        case 2: src = v;  off = 2 * BSD;      break;
        case 3: src = Wq; off = 3 * BSD;      break;
        case 4: src = Wk; off = 3 * BSD + MM; break;
        case 5: src = Wv; off = 3 * BSD + 2 * MM; break;
        default: src = Wo; off = 3 * BSD + 3 * MM; break;
    }
    f32x4 a = *(const f32x4*)(src + i);
    f32x4 b = *(const f32x4*)(src + i + 4);
    bf16x8 r;
    #pragma unroll
    for (int j = 0; j < 4; j++) { r[j] = (short)f2bf(a[j]); r[j + 4] = (short)f2bf(b[j]); }
    *(bf16x8*)(dst + off + i) = r;
}

// ---------------------------------------------------------------------------
// Stage one 128x32 bf16 tile into LDS via global_load_lds (width 16).
// Chunk c = wave*128 + j*64 + lane; row = c>>2, k8 = c&3; LDS dest is the
// wave-uniform base + lane*16 that the HW enforces.
// ---------------------------------------------------------------------------
__device__ inline void stage_tile(const ushort* __restrict__ G, int ld, int rowbase,
                                  int kt, ushort* lds, int wave, int lane)
{
    #pragma unroll
    for (int j = 0; j < 2; j++) {
        const int c = wave * 128 + j * 64 + lane;
        const int row = c >> 2, k8 = c & 3;
        const ushort* g = G + (long)(rowbase + row) * ld + kt + k8 * 8;
        ushort* l = lds + (wave * 128 + j * 64) * 8;   // wave-uniform base
        __builtin_amdgcn_global_load_lds(
            (const __attribute__((address_space(1))) u32*)(const void*)g,
            (__attribute__((address_space(3))) u32*)(void*)l, 16, 0, 0);
    }
}

// ---------------------------------------------------------------------------
// m97-ladder GEMM: C[m,n] = sum_k A[m,k]*Bt[n,k] (+bias[n]).
// 128x128 block tile, BK=32, 256 threads (2x2 waves of 64x64), double-buffered
// LDS with ONE barrier per k-iter (prefetch issued before compute so it flies
// during the MFMA phase; the barrier's vmcnt(0) drain lands after compute).
// MODE 0: bf16 out, C[r*ldc + col]
// MODE 1: bf16 out, Vt scatter Vt[((b*H+h)*HD+d)*S + s]
// MODE 2: fp32 out, C[r*ldc + col]
// ---------------------------------------------------------------------------
template<int MODE>
__global__ __launch_bounds__(256)
void gemm_big(const ushort* __restrict__ A, int lda,
              const ushort* __restrict__ Bt, int ldb,
              const float* __restrict__ bias,
              void* __restrict__ Cv, int ldc, int K)
{
    __shared__ ushort As[2][128 * 32];
    __shared__ ushort Bs[2][128 * 32];

    const int tid = threadIdx.x;
    const int lane = tid & 63, wave = tid >> 6;
    const int l15 = lane & 15, quad = lane >> 4;
    const int wr = wave >> 1, wc = wave & 1;
    const int mtile = blockIdx.y * 128, ntile = blockIdx.x * 128;

    f32x4 acc[4][4] = {};

    stage_tile(A,  lda, mtile, 0, As[0], wave, lane);
    stage_tile(Bt, ldb, ntile, 0, Bs[0], wave, lane);
    __syncthreads();

    int buf = 0;
    for (int kt = 0; kt < K; kt += 32) {
        if (kt + 32 < K) {
            stage_tile(A,  lda, mtile, kt + 32, As[buf ^ 1], wave, lane);
            stage_tile(Bt, ldb, ntile, kt + 32, Bs[buf ^ 1], wave, lane);
        }
        bf16x8 af[4], bfr[4];
        #pragma unroll
        for (int mt = 0; mt < 4; mt++)
            af[mt] = *(const bf16x8*)(As[buf] + (wr * 64 + mt * 16 + l15) * 32 + quad * 8);
        #pragma unroll
        for (int nt = 0; nt < 4; nt++)
            bfr[nt] = *(const bf16x8*)(Bs[buf] + (wc * 64 + nt * 16 + l15) * 32 + quad * 8);
        #pragma unroll
        for (int mt = 0; mt < 4; mt++)
            #pragma unroll
            for (int nt = 0; nt < 4; nt++)
                acc[mt][nt] = __builtin_amdgcn_mfma_f32_16x16x32_bf16(af[mt], bfr[nt], acc[mt][nt], 0, 0, 0);
        __syncthreads();   // drains prefetch vmcnt + protects LDS reuse
        buf ^= 1;
    }

    // Epilogue. C/D layout: col = lane&15, row = quad*4 + reg.
    #pragma unroll
    for (int mt = 0; mt < 4; mt++) {
        #pragma unroll
        for (int nt = 0; nt < 4; nt++) {
            const int col = ntile + wc * 64 + nt * 16 + l15;
            const float bv = bias ? bias[col] : 0.0f;
            #pragma unroll
            for (int i = 0; i < 4; i++) {
                const int r = mtile + wr * 64 + mt * 16 + quad * 4 + i;
                const float vv = acc[mt][nt][i] + bv;
                if (MODE == 0) {
                    ((ushort*)Cv)[(long)r * ldc + col] = f2bf(vv);
                } else if (MODE == 2) {
                    ((float*)Cv)[(long)r * ldc + col] = vv;
                } else {
                    // r = b*S + s ; col = h*HD + d
                    const int b = r >> 10, s = r & 1023;
                    const int h = col >> 6, d = col & 63;
                    ((ushort*)Cv)[(long)((b * Hc + h) * HDc + d) * Sc + s] = f2bf(vv);
                }
            }
        }
    }
}

// ---------------------------------------------------------------------------
// Fused scores + mask + softmax -> writes fp32 attn (the 2nd output).
// Grid: (S/16 q-blocks, B*H). Block 256 (4 waves). WG owns 16 q-rows, all 1024 k.
// ---------------------------------------------------------------------------
__global__ __launch_bounds__(256)
void attn_softmax(const ushort* __restrict__ Q, const ushort* __restrict__ Kp,
                  const int* __restrict__ mask, float* __restrict__ attn)
{
    __shared__ float sc[16][1024];   // 64 KB

    const int bh = blockIdx.y;
    const int b = bh >> 4, h = bh & 15;
    const int qbase = blockIdx.x * 16;
    const int lane = threadIdx.x & 63;
    const int wave = threadIdx.x >> 6;
    const int l15 = lane & 15, quad = lane >> 4;

    const ushort* Qh = Q  + (long)b * Sc * Dc + h * HDc;
    const ushort* Kh = Kp + (long)b * Sc * Dc + h * HDc;

    const ushort* qrow = Qh + (long)(qbase + l15) * Dc + quad * 8;
    const bf16x8 a0 = *(const bf16x8*)(qrow);
    const bf16x8 a1 = *(const bf16x8*)(qrow + 32);

    for (int t = 0; t < 16; t++) {
        const int ct = wave * 16 + t;
        const ushort* krow = Kh + (long)(ct * 16 + l15) * Dc + quad * 8;
        const bf16x8 b0 = *(const bf16x8*)(krow);
        const bf16x8 b1 = *(const bf16x8*)(krow + 32);
        f32x4 acc = {};
        acc = __builtin_amdgcn_mfma_f32_16x16x32_bf16(a0, b0, acc, 0, 0, 0);
        acc = __builtin_amdgcn_mfma_f32_16x16x32_bf16(a1, b1, acc, 0, 0, 0);
        const int col = ct * 16 + l15;
        #pragma unroll
        for (int i = 0; i < 4; i++) sc[quad * 4 + i][col] = acc[i];
    }
    __syncthreads();

    for (int rr = 0; rr < 4; rr++) {
        const int r = wave * 4 + rr;
        float v[16];
        float mx = -3.0e38f;
        #pragma unroll
        for (int t = 0; t < 16; t++) {
            const int col = t * 64 + lane;
            float s = sc[r][col] * 0.125f;                 // 1/sqrt(64)
            if (mask[b * Sc + col] == 0) s = -1e10f;
            v[t] = s;
            mx = fmaxf(mx, s);
        }
        #pragma unroll
        for (int off = 32; off >= 1; off >>= 1) mx = fmaxf(mx, __shfl_xor(mx, off, 64));
        float sum = 0.0f;
        #pragma unroll
        for (int t = 0; t < 16; t++) { v[t] = __expf(v[t] - mx); sum += v[t]; }
        #pragma unroll
        for (int off = 32; off >= 1; off >>= 1) sum += __shfl_xor(sum, off, 64);
        const float inv = 1.0f / sum;
        float* arow = attn + ((long)bh * Sc + qbase + r) * Sc;
        #pragma unroll
        for (int t = 0; t < 16; t++) arow[t * 64 + lane] = v[t] * inv;
    }
}

// ---------------------------------------------------------------------------
// ctx = attn @ V, batched over z = b*H + h. A = attn fp32 (converted inline),
// Bt = Vt[b,h,d,s] bf16. Out: Ctx bf16 in (B,S,D) head-interleaved layout.
// Block tile 64x64 (grid.x=1 covers N=64), m90-style (HBM-bound on attn read).
// ---------------------------------------------------------------------------
__global__ __launch_bounds__(256)
void gemm_ctx(const float* __restrict__ Attn, const ushort* __restrict__ Vt,
              ushort* __restrict__ Ctx)
{
    const int z = blockIdx.z;
    const float*  Af = Attn + (long)z * Sc * Sc;
    const ushort* Bt = Vt + (long)z * HDc * Sc;

    const int lane = threadIdx.x & 63;
    const int wave = threadIdx.x >> 6;
    const int wr = wave >> 1, wc = wave & 1;
    const int mbase = blockIdx.y * 64 + wr * 32;
    const int nbase = wc * 32;
    const int l15 = lane & 15, quad = lane >> 4;

    f32x4 acc00 = {}, acc01 = {}, acc10 = {}, acc11 = {};

    const float*  af0 = Af + (long)(mbase      + l15) * Sc + quad * 8;
    const float*  af1 = Af + (long)(mbase + 16 + l15) * Sc + quad * 8;
    const ushort* bb0 = Bt + (long)(nbase      + l15) * Sc + quad * 8;
    const ushort* bb1 = Bt + (long)(nbase + 16 + l15) * Sc + quad * 8;

    for (int k0 = 0; k0 < Sc; k0 += 32) {
        bf16x8 a0 = frag_f32(af0 + k0);
        bf16x8 a1 = frag_f32(af1 + k0);
        bf16x8 b0 = *(const bf16x8*)(bb0 + k0);
        bf16x8 b1 = *(const bf16x8*)(bb1 + k0);
        acc00 = __builtin_amdgcn_mfma_f32_16x16x32_bf16(a0, b0, acc00, 0, 0, 0);
        acc01 = __builtin_amdgcn_mfma_f32_16x16x32_bf16(a0, b1, acc01, 0, 0, 0);
        acc10 = __builtin_amdgcn_mfma_f32_16x16x32_bf16(a1, b0, acc10, 0, 0, 0);
        acc11 = __builtin_amdgcn_mfma_f32_16x16x32_bf16(a1, b1, acc11, 0, 0, 0);
    }

    const int b = z >> 4, h = z & 15;
    f32x4 accs[2][2] = { {acc00, acc01}, {acc10, acc11} };
    #pragma unroll
    for (int mt = 0; mt < 2; mt++) {
        #pragma unroll
        for (int nt = 0; nt < 2; nt++) {
            const int row0 = mbase + mt * 16 + quad * 4;
            const int col  = nbase + nt * 16 + l15;
            #pragma unroll
            for (int i = 0; i < 4; i++) {
                const int r = row0 + i;
                Ctx[(long)b * Sc * Dc + (long)r * Dc + h * HDc + col] = f2bf(accs[mt][nt][i]);
            }
        }
    }
}

// ---------------------------------------------------------------------------
extern "C" void kernel_launch(void* const* d_in, const int* in_sizes, int n_in,
                              void* d_out, int out_size, void* d_ws, size_t ws_size,
                              hipStream_t stream)
{
    const float* q    = (const float*)d_in[0];
    const float* k    = (const float*)d_in[1];
    const float* v    = (const float*)d_in[2];
    const int*   mask = (const int*)  d_in[3];
    const float* bq   = (const float*)d_in[5];
    const float* bk   = (const float*)d_in[7];
    const float* bv   = (const float*)d_in[9];
    const float* Wq   = (const float*)d_in[4];
    const float* Wk   = (const float*)d_in[6];
    const float* Wv   = (const float*)d_in[8];
    const float* Wo   = (const float*)d_in[10];
    const float* bo   = (const float*)d_in[11];

    ushort* ws  = (ushort*)d_ws;
    ushort* qb  = ws;                        // bf16 q,k,v (BSD each)
    ushort* kb  = ws + BSD;
    ushort* vb  = ws + 2 * BSD;
    ushort* Wqb = ws + 3 * BSD;              // bf16 weights (MM each)
    ushort* Wkb = Wqb + MM;
    ushort* Wvb = Wkb + MM;
    ushort* Wob = Wvb + MM;
    ushort* Qp  = ws + 3 * BSD + 4 * MM;     // projected Q,K bf16
    ushort* Kpp = Qp + BSD;
    ushort* Vt  = Kpp + BSD;                 // Vt[b,h,d,s] bf16
    ushort* Ctx = Vt + BSD;                  // ctx bf16, (B,S,D) layout

    float* out  = (float*)d_out;             // output 0: (B,S,D) fp32
    float* attn = out + BSD;                 // output 1: (B,H,S,S) fp32

    const dim3 blk(256);

    // fp32 -> bf16 converts (one launch, 7 tensors)
    cvt_all<<<dim3(BSD / (256 * 8), 7), blk, 0, stream>>>(q, k, v, Wq, Wk, Wv, Wo, ws);

    // Projections: M=4096 (grid.y=32), N=1024 (grid.x=8), K=1024.
    gemm_big<0><<<dim3(8, 32), blk, 0, stream>>>(qb, Dc, Wqb, Dc, bq, Qp,  Dc, Dc);
    gemm_big<0><<<dim3(8, 32), blk, 0, stream>>>(kb, Dc, Wkb, Dc, bk, Kpp, Dc, Dc);
    gemm_big<1><<<dim3(8, 32), blk, 0, stream>>>(vb, Dc, Wvb, Dc, bv, Vt,  0,  Dc);

    // Scores + mask + softmax -> attn (fp32, into d_out).
    attn_softmax<<<dim3(Sc / 16, Bc * Hc), blk, 0, stream>>>(Qp, Kpp, mask, attn);

    // ctx = attn @ V : batched over 64 (b,h); M=1024, N=64, K=1024.
    gemm_ctx<<<dim3(1, 16, Bc * Hc), blk, 0, stream>>>(attn, Vt, Ctx);

    // out = ctx @ Wo^T + bo -> d_out[0 : B*S*D]  (fp32 out).
    gemm_big<2><<<dim3(8, 32), blk, 0, stream>>>(Ctx, Dc, Wob, Dc, bo, out, Dc, Dc);
}